// Round 1
// baseline (10361.327 us; speedup 1.0000x reference)
//
#include <hip/hip_runtime.h>
#include <math.h>

// Problem constants (match reference)
constexpr int kE = 32;    // experts
constexpr int kH = 2048;  // hidden
constexpr int kI = 768;   // expert intermediate dim
constexpr int kT = 2048;  // tokens
constexpr int kK = 4;     // top-k

// Workspace layout (bytes):
//   [0,   256)                : expert_offsets int[kE+1]
//   [256, 256+32768)          : token_ids int[kT*kK]
//   [33024, 65792)            : token_w  float[kT*kK]
//   [65792, 65792+8192*768*4) : gated    float[slots][kI]   (~25.2 MB)
constexpr size_t kOffsOff  = 0;
constexpr size_t kTokOff   = 256;
constexpr size_t kTwOff    = 256 + (size_t)kT * kK * 4;
constexpr size_t kGatedOff = 65792;

// ---------------------------------------------------------------------------
// Routing: build per-expert token lists. Single block (T*K = 8192 items).
// numpy scatter semantics: for duplicate experts within a token's top-k, the
// LAST occurrence's weight wins and the expert contributes exactly once.
// ---------------------------------------------------------------------------
__global__ __launch_bounds__(256) void route_kernel(
    const int* __restrict__ ridx, const float* __restrict__ rw,
    int* __restrict__ offs, int* __restrict__ tok, float* __restrict__ tw) {
  __shared__ int s_cnt[kE];
  __shared__ int s_off[kE + 1];
  __shared__ int s_cur[kE];
  const int tid = threadIdx.x;
  if (tid < kE) { s_cnt[tid] = 0; s_cur[tid] = 0; }
  __syncthreads();
  for (int i = tid; i < kT * kK; i += 256) {
    const int t = i >> 2, k = i & 3;
    const int e = ridx[i];
    bool last = true;
    for (int k2 = k + 1; k2 < kK; ++k2)
      if (ridx[t * kK + k2] == e) last = false;
    if (last) atomicAdd(&s_cnt[e], 1);
  }
  __syncthreads();
  if (tid == 0) {
    int acc = 0;
    for (int e = 0; e < kE; ++e) { s_off[e] = acc; acc += s_cnt[e]; }
    s_off[kE] = acc;
  }
  __syncthreads();
  if (tid <= kE) offs[tid] = s_off[tid];
  for (int i = tid; i < kT * kK; i += 256) {
    const int t = i >> 2, k = i & 3;
    const int e = ridx[i];
    bool last = true;
    for (int k2 = k + 1; k2 < kK; ++k2)
      if (ridx[t * kK + k2] == e) last = false;
    if (last) {
      const int p = atomicAdd(&s_cur[e], 1);
      const int g = s_off[e] + p;
      tok[g] = t;
      tw[g] = rw[i];
    }
  }
}

// ---------------------------------------------------------------------------
// Stage 2: per-expert gate_up GEMM + SwiGLU.
// grid.x = 32 experts * 32 token-tiles (64 tokens each), grid.y = I/64 = 12.
// Block: 256 threads, 64x64 output tile (x2: gate and up), 4x4 per thread.
// ---------------------------------------------------------------------------
__global__ __launch_bounds__(256) void gateup_kernel(
    const float* __restrict__ hs, const float* __restrict__ gup,
    const int* __restrict__ offs, const int* __restrict__ tok,
    float* __restrict__ gated) {
  const int e  = blockIdx.x >> 5;
  const int tt = blockIdx.x & 31;
  const int base = offs[e];
  const int Ne = offs[e + 1] - base;
  if (tt * 64 >= Ne) return;
  const int i0 = blockIdx.y * 64;
  const int total = offs[kE];

  __shared__ float As[64][17];
  __shared__ float Bg[16][65];
  __shared__ float Bu[16][65];

  const int tid = threadIdx.x;
  // A-load mapping: 64 rows x 16 k, float4 per thread
  const int lr  = tid >> 2;
  const int lc4 = (tid & 3) * 4;
  const int slot = base + tt * 64 + lr;
  const int slotc = slot < total ? slot : total - 1;
  const size_t tokrow = (size_t)tok[slotc] * kH;
  // B-load mapping: 16 k-rows x 64 cols, float4 per thread
  const int bl  = tid >> 4;
  const int bi4 = (tid & 15) * 4;
  const float* gupe = gup + (size_t)e * kH * (2 * kI);

  float ag[4][4] = {{0.f}}, au[4][4] = {{0.f}};
  const int tr = tid >> 4, tc = tid & 15;

  for (int kk = 0; kk < kH; kk += 16) {
    const float4 av = *(const float4*)(hs + tokrow + kk + lc4);
    As[lr][lc4 + 0] = av.x; As[lr][lc4 + 1] = av.y;
    As[lr][lc4 + 2] = av.z; As[lr][lc4 + 3] = av.w;
    const float* bp = gupe + (size_t)(kk + bl) * (2 * kI) + i0 + bi4;
    const float4 bgv = *(const float4*)bp;
    const float4 buv = *(const float4*)(bp + kI);
    Bg[bl][bi4 + 0] = bgv.x; Bg[bl][bi4 + 1] = bgv.y;
    Bg[bl][bi4 + 2] = bgv.z; Bg[bl][bi4 + 3] = bgv.w;
    Bu[bl][bi4 + 0] = buv.x; Bu[bl][bi4 + 1] = buv.y;
    Bu[bl][bi4 + 2] = buv.z; Bu[bl][bi4 + 3] = buv.w;
    __syncthreads();
#pragma unroll
    for (int k = 0; k < 16; ++k) {
      float a[4], bg4[4], bu4[4];
#pragma unroll
      for (int j = 0; j < 4; ++j) a[j] = As[tr * 4 + j][k];
#pragma unroll
      for (int j = 0; j < 4; ++j) { bg4[j] = Bg[k][tc * 4 + j]; bu4[j] = Bu[k][tc * 4 + j]; }
#pragma unroll
      for (int r = 0; r < 4; ++r)
#pragma unroll
        for (int c = 0; c < 4; ++c) {
          ag[r][c] += a[r] * bg4[c];
          au[r][c] += a[r] * bu4[c];
        }
    }
    __syncthreads();
  }

#pragma unroll
  for (int r = 0; r < 4; ++r) {
    const int row = tr * 4 + r;
    if (tt * 64 + row < Ne) {
      float* op = gated + (size_t)(base + tt * 64 + row) * kI + i0 + tc * 4;
      float4 v;
      float g;
      g = ag[r][0]; v.x = au[r][0] * (g / (1.f + expf(-g)));
      g = ag[r][1]; v.y = au[r][1] * (g / (1.f + expf(-g)));
      g = ag[r][2]; v.z = au[r][2] * (g / (1.f + expf(-g)));
      g = ag[r][3]; v.w = au[r][3] * (g / (1.f + expf(-g)));
      *(float4*)op = v;
    }
  }
}

// ---------------------------------------------------------------------------
// Stage 3: per-expert down GEMM, scale by routing weight, atomicAdd into out.
// grid.x = 1024 token-tiles, grid.y = H/64 = 32.
// ---------------------------------------------------------------------------
__global__ __launch_bounds__(256) void down_kernel(
    const float* __restrict__ gated, const float* __restrict__ dn,
    const int* __restrict__ offs, const int* __restrict__ tok,
    const float* __restrict__ tw, float* __restrict__ out) {
  const int e  = blockIdx.x >> 5;
  const int tt = blockIdx.x & 31;
  const int base = offs[e];
  const int Ne = offs[e + 1] - base;
  if (tt * 64 >= Ne) return;
  const int h0 = blockIdx.y * 64;
  const int total = offs[kE];

  __shared__ float As[64][17];
  __shared__ float Bs[16][65];

  const int tid = threadIdx.x;
  const int lr  = tid >> 2;
  const int lc4 = (tid & 3) * 4;
  const int slot = base + tt * 64 + lr;
  const int slotc = slot < total ? slot : total - 1;
  const float* arow = gated + (size_t)slotc * kI;
  const int bl  = tid >> 4;
  const int bi4 = (tid & 15) * 4;
  const float* dne = dn + (size_t)e * kI * kH;

  float acc[4][4] = {{0.f}};
  const int tr = tid >> 4, tc = tid & 15;

  for (int kk = 0; kk < kI; kk += 16) {
    const float4 av = *(const float4*)(arow + kk + lc4);
    As[lr][lc4 + 0] = av.x; As[lr][lc4 + 1] = av.y;
    As[lr][lc4 + 2] = av.z; As[lr][lc4 + 3] = av.w;
    const float4 bv = *(const float4*)(dne + (size_t)(kk + bl) * kH + h0 + bi4);
    Bs[bl][bi4 + 0] = bv.x; Bs[bl][bi4 + 1] = bv.y;
    Bs[bl][bi4 + 2] = bv.z; Bs[bl][bi4 + 3] = bv.w;
    __syncthreads();
#pragma unroll
    for (int k = 0; k < 16; ++k) {
      float a[4], b4[4];
#pragma unroll
      for (int j = 0; j < 4; ++j) a[j] = As[tr * 4 + j][k];
#pragma unroll
      for (int j = 0; j < 4; ++j) b4[j] = Bs[k][tc * 4 + j];
#pragma unroll
      for (int r = 0; r < 4; ++r)
#pragma unroll
        for (int c = 0; c < 4; ++c) acc[r][c] += a[r] * b4[c];
    }
    __syncthreads();
  }

#pragma unroll
  for (int r = 0; r < 4; ++r) {
    const int row = tr * 4 + r;
    const int idx = tt * 64 + row;
    if (idx < Ne) {
      const int s = base + idx;
      const int t = tok[s];
      const float w = tw[s];
      float* op = out + (size_t)t * kH + h0 + tc * 4;
#pragma unroll
      for (int c = 0; c < 4; ++c) atomicAdd(&op[c], acc[r][c] * w);
    }
  }
}

extern "C" void kernel_launch(void* const* d_in, const int* in_sizes, int n_in,
                              void* d_out, int out_size, void* d_ws, size_t ws_size,
                              hipStream_t stream) {
  const float* hs   = (const float*)d_in[0];  // hidden_states [T,H]
  const float* rw   = (const float*)d_in[1];  // routing_weights [T,K]
  const int*   ridx = (const int*)d_in[2];    // router_indices [T,K]
  // d_in[3] router_logits: only used for shape in reference
  const float* gup  = (const float*)d_in[4];  // [E*H, 2I]
  const float* dn   = (const float*)d_in[5];  // [E*I, H]
  float* out = (float*)d_out;

  char* ws = (char*)d_ws;
  int*   offs  = (int*)(ws + kOffsOff);
  int*   tok   = (int*)(ws + kTokOff);
  float* tw    = (float*)(ws + kTwOff);
  float* gated = (float*)(ws + kGatedOff);

  hipMemsetAsync(d_out, 0, (size_t)kT * kH * sizeof(float), stream);
  route_kernel<<<1, 256, 0, stream>>>(ridx, rw, offs, tok, tw);
  gateup_kernel<<<dim3(32 * 32, kI / 64), 256, 0, stream>>>(hs, gup, offs, tok, gated);
  down_kernel<<<dim3(32 * 32, kH / 64), 256, 0, stream>>>(gated, dn, offs, tok, tw, out);
}

// Round 2
// 1917.556 us; speedup vs baseline: 5.4034x; 5.4034x over previous
//
#include <hip/hip_runtime.h>
#include <math.h>

constexpr int kE = 32;    // experts
constexpr int kH = 2048;  // hidden
constexpr int kI = 768;   // expert intermediate dim
constexpr int kT = 2048;  // tokens
constexpr int kK = 4;     // top-k

typedef _Float16 half8  __attribute__((ext_vector_type(8)));
typedef _Float16 half4v __attribute__((ext_vector_type(4)));
typedef float    float4v __attribute__((ext_vector_type(4)));

// Workspace layout (bytes):
//   [0,256)    expert_offsets int[kE+1]
//   [256,..)   token_ids int[8192]
//   then       token_w  float[8192]
//   [65792,..) gated    _Float16[8192][768]  (~12.6 MB)
constexpr size_t kOffsOff  = 0;
constexpr size_t kTokOff   = 256;
constexpr size_t kTwOff    = 256 + (size_t)kT * kK * 4;
constexpr size_t kGatedOff = 65792;

// ---------------------------------------------------------------------------
// Routing (unchanged from R1 — verified correct). numpy scatter semantics:
// last duplicate wins, expert contributes once.
// ---------------------------------------------------------------------------
__global__ __launch_bounds__(256) void route_kernel(
    const int* __restrict__ ridx, const float* __restrict__ rw,
    int* __restrict__ offs, int* __restrict__ tok, float* __restrict__ tw) {
  __shared__ int s_cnt[kE];
  __shared__ int s_off[kE + 1];
  __shared__ int s_cur[kE];
  const int tid = threadIdx.x;
  if (tid < kE) { s_cnt[tid] = 0; s_cur[tid] = 0; }
  __syncthreads();
  for (int i = tid; i < kT * kK; i += 256) {
    const int t = i >> 2, k = i & 3;
    const int e = ridx[i];
    bool last = true;
    for (int k2 = k + 1; k2 < kK; ++k2)
      if (ridx[t * kK + k2] == e) last = false;
    if (last) atomicAdd(&s_cnt[e], 1);
  }
  __syncthreads();
  if (tid == 0) {
    int acc = 0;
    for (int e = 0; e < kE; ++e) { s_off[e] = acc; acc += s_cnt[e]; }
    s_off[kE] = acc;
  }
  __syncthreads();
  if (tid <= kE) offs[tid] = s_off[tid];
  for (int i = tid; i < kT * kK; i += 256) {
    const int t = i >> 2, k = i & 3;
    const int e = ridx[i];
    bool last = true;
    for (int k2 = k + 1; k2 < kK; ++k2)
      if (ridx[t * kK + k2] == e) last = false;
    if (last) {
      const int p = atomicAdd(&s_cur[e], 1);
      const int g = s_off[e] + p;
      tok[g] = t;
      tw[g] = rw[i];
    }
  }
}

// ---------------------------------------------------------------------------
// Gate-up MFMA kernel. Block: 256 thr = 4 waves. Tile: 128 tokens x
// (64 gate cols + 64 up cols). Wave (wm,wn): 64 rows x (32 gate + 32 up).
// MFMA 16x16x32 f16, fp32 acc. LDS rows padded to 40 halves (80 B) so
// fragment ds_read_b128 is ~2-way (free).
// ---------------------------------------------------------------------------
__global__ __launch_bounds__(256) void gateup_kernel(
    const float* __restrict__ hs, const float* __restrict__ gup,
    const int* __restrict__ offs, const int* __restrict__ tok,
    _Float16* __restrict__ gated) {
  const int e  = blockIdx.x >> 4;
  const int tt = blockIdx.x & 15;
  const int base = offs[e];
  const int Ne = offs[e + 1] - base;
  if (tt * 128 >= Ne) return;
  const int i0 = blockIdx.y * 64;
  const int total = offs[kE];

  __shared__ _Float16 Asb[128 * 40];  // [row][k] k-contiguous, stride 40
  __shared__ _Float16 Bsb[128 * 40];  // [n][k] transposed; n<64 gate, n>=64 up

  const int tid = threadIdx.x;
  // A staging: thread covers rows ar+32i (i<4), k-chunk ak0..ak0+3
  const int ar  = tid >> 3;
  const int ak0 = (tid & 7) * 4;
  size_t arow[4];
#pragma unroll
  for (int i = 0; i < 4; ++i) {
    int slot = base + tt * 128 + ar + 32 * i;
    slot = slot < total ? slot : total - 1;
    arow[i] = (size_t)tok[slot] * kH;
  }
  // B staging: thread owns col n=bn, k-chunks bk+16p (p<2), 4 k each
  const int bn = tid & 63;
  const int bk = (tid >> 6) * 4;
  const float* gupe = gup + (size_t)e * kH * (2 * kI);

  const int lane = tid & 63, wave = tid >> 6;
  const int m16 = lane & 15, quad = lane >> 4;
  const int wm = wave >> 1, wn = wave & 1;

  float4v accg[4][2], accu[4][2];
#pragma unroll
  for (int mt = 0; mt < 4; ++mt)
#pragma unroll
    for (int nt = 0; nt < 2; ++nt) {
      accg[mt][nt] = (float4v){0.f, 0.f, 0.f, 0.f};
      accu[mt][nt] = (float4v){0.f, 0.f, 0.f, 0.f};
    }

  for (int kk = 0; kk < kH; kk += 32) {
    // issue global loads
    float4 av[4];
#pragma unroll
    for (int i = 0; i < 4; ++i)
      av[i] = *(const float4*)(hs + arow[i] + kk + ak0);
    float bg[2][4], bu[2][4];
#pragma unroll
    for (int p = 0; p < 2; ++p) {
      const int k0 = bk + 16 * p;
      const float* bp = gupe + (size_t)(kk + k0) * (2 * kI) + i0 + bn;
#pragma unroll
      for (int j = 0; j < 4; ++j) {
        bg[p][j] = bp[(size_t)j * (2 * kI)];
        bu[p][j] = bp[(size_t)j * (2 * kI) + kI];
      }
    }
    __syncthreads();  // protect previous iteration's fragment reads
#pragma unroll
    for (int i = 0; i < 4; ++i)
      *(half4v*)&Asb[(ar + 32 * i) * 40 + ak0] =
          (half4v){(_Float16)av[i].x, (_Float16)av[i].y,
                   (_Float16)av[i].z, (_Float16)av[i].w};
#pragma unroll
    for (int p = 0; p < 2; ++p) {
      const int k0 = bk + 16 * p;
      *(half4v*)&Bsb[bn * 40 + k0] =
          (half4v){(_Float16)bg[p][0], (_Float16)bg[p][1],
                   (_Float16)bg[p][2], (_Float16)bg[p][3]};
      *(half4v*)&Bsb[(bn + 64) * 40 + k0] =
          (half4v){(_Float16)bu[p][0], (_Float16)bu[p][1],
                   (_Float16)bu[p][2], (_Float16)bu[p][3]};
    }
    __syncthreads();
    half8 af[4];
#pragma unroll
    for (int mt = 0; mt < 4; ++mt)
      af[mt] = *(const half8*)&Asb[(wm * 64 + mt * 16 + m16) * 40 + quad * 8];
    half8 bfg[2], bfu[2];
#pragma unroll
    for (int nt = 0; nt < 2; ++nt) {
      bfg[nt] = *(const half8*)&Bsb[(wn * 32 + nt * 16 + m16) * 40 + quad * 8];
      bfu[nt] = *(const half8*)&Bsb[(64 + wn * 32 + nt * 16 + m16) * 40 + quad * 8];
    }
#pragma unroll
    for (int mt = 0; mt < 4; ++mt)
#pragma unroll
      for (int nt = 0; nt < 2; ++nt) {
        accg[mt][nt] = __builtin_amdgcn_mfma_f32_16x16x32_f16(
            af[mt], bfg[nt], accg[mt][nt], 0, 0, 0);
        accu[mt][nt] = __builtin_amdgcn_mfma_f32_16x16x32_f16(
            af[mt], bfu[nt], accu[mt][nt], 0, 0, 0);
      }
  }
  // epilogue: SwiGLU, store fp16 gated. D layout: row=quad*4+r, col=m16.
#pragma unroll
  for (int mt = 0; mt < 4; ++mt)
#pragma unroll
    for (int r = 0; r < 4; ++r) {
      const int rr = tt * 128 + wm * 64 + mt * 16 + quad * 4 + r;
      if (rr < Ne) {
        _Float16* gp = gated + (size_t)(base + rr) * kI + i0 + wn * 32 + m16;
#pragma unroll
        for (int nt = 0; nt < 2; ++nt) {
          const float g = accg[mt][nt][r];
          const float u = accu[mt][nt][r];
          gp[nt * 16] = (_Float16)(u * g / (1.f + expf(-g)));
        }
      }
    }
}

// ---------------------------------------------------------------------------
// Down-proj MFMA kernel. Block tile: 128 slots x 128 H-cols. Wave: 64x64.
// A = gated (fp16, direct b128 staging), B = down weights (fp32, transposed
// into LDS with on-the-fly conversion). Epilogue: scale by routing weight,
// atomicAdd into out.
// ---------------------------------------------------------------------------
__global__ __launch_bounds__(256) void down_kernel(
    const _Float16* __restrict__ gated, const float* __restrict__ dn,
    const int* __restrict__ offs, const int* __restrict__ tok,
    const float* __restrict__ tw, float* __restrict__ out) {
  const int e  = blockIdx.x >> 4;
  const int tt = blockIdx.x & 15;
  const int base = offs[e];
  const int Ne = offs[e + 1] - base;
  if (tt * 128 >= Ne) return;
  const int h0 = blockIdx.y * 128;
  const int total = offs[kE];

  __shared__ _Float16 Asb[128 * 40];
  __shared__ _Float16 Bsb[128 * 40];

  const int tid = threadIdx.x;
  // A staging: units u = tid + 256i (i<2): row = u>>2, k8 = (u&3)*8
  const int ar  = tid >> 2;         // 0..63 (+64i)
  const int ak8 = (tid & 3) * 8;
  size_t arow[2];
#pragma unroll
  for (int i = 0; i < 2; ++i) {
    int slot = base + tt * 128 + ar + 64 * i;
    slot = slot < total ? slot : total - 1;
    arow[i] = (size_t)slot * kI;
  }
  // B staging: col n = tid&127; k-chunks bk+8g (g<4), 4 k each
  const int bn = tid & 127;
  const int bk = (tid >> 7) * 4;    // 0 or 4
  const float* dne = dn + (size_t)e * kI * kH;

  const int lane = tid & 63, wave = tid >> 6;
  const int m16 = lane & 15, quad = lane >> 4;
  const int wm = wave >> 1, wn = wave & 1;

  float4v acc[4][4];
#pragma unroll
  for (int mt = 0; mt < 4; ++mt)
#pragma unroll
    for (int nt = 0; nt < 4; ++nt) acc[mt][nt] = (float4v){0.f, 0.f, 0.f, 0.f};

  for (int kk = 0; kk < kI; kk += 32) {
    half8 a8[2];
#pragma unroll
    for (int i = 0; i < 2; ++i)
      a8[i] = *(const half8*)(gated + arow[i] + kk + ak8);
    float bw[4][4];
#pragma unroll
    for (int g = 0; g < 4; ++g) {
      const int k0 = bk + 8 * g;
#pragma unroll
      for (int j = 0; j < 4; ++j)
        bw[g][j] = dne[(size_t)(kk + k0 + j) * kH + h0 + bn];
    }
    __syncthreads();
#pragma unroll
    for (int i = 0; i < 2; ++i)
      *(half8*)&Asb[(ar + 64 * i) * 40 + ak8] = a8[i];
#pragma unroll
    for (int g = 0; g < 4; ++g) {
      const int k0 = bk + 8 * g;
      *(half4v*)&Bsb[bn * 40 + k0] =
          (half4v){(_Float16)bw[g][0], (_Float16)bw[g][1],
                   (_Float16)bw[g][2], (_Float16)bw[g][3]};
    }
    __syncthreads();
    half8 af[4], bf[4];
#pragma unroll
    for (int mt = 0; mt < 4; ++mt)
      af[mt] = *(const half8*)&Asb[(wm * 64 + mt * 16 + m16) * 40 + quad * 8];
#pragma unroll
    for (int nt = 0; nt < 4; ++nt)
      bf[nt] = *(const half8*)&Bsb[(wn * 64 + nt * 16 + m16) * 40 + quad * 8];
#pragma unroll
    for (int mt = 0; mt < 4; ++mt)
#pragma unroll
      for (int nt = 0; nt < 4; ++nt)
        acc[mt][nt] = __builtin_amdgcn_mfma_f32_16x16x32_f16(
            af[mt], bf[nt], acc[mt][nt], 0, 0, 0);
  }
  // epilogue
#pragma unroll
  for (int mt = 0; mt < 4; ++mt)
#pragma unroll
    for (int r = 0; r < 4; ++r) {
      const int rr = tt * 128 + wm * 64 + mt * 16 + quad * 4 + r;
      if (rr < Ne) {
        const int s = base + rr;
        const int t = tok[s];
        const float w = tw[s];
        float* op = out + (size_t)t * kH + h0 + wn * 64 + m16;
#pragma unroll
        for (int nt = 0; nt < 4; ++nt)
          atomicAdd(&op[nt * 16], acc[mt][nt][r] * w);
      }
    }
}

extern "C" void kernel_launch(void* const* d_in, const int* in_sizes, int n_in,
                              void* d_out, int out_size, void* d_ws, size_t ws_size,
                              hipStream_t stream) {
  const float* hs   = (const float*)d_in[0];
  const float* rw   = (const float*)d_in[1];
  const int*   ridx = (const int*)d_in[2];
  const float* gup  = (const float*)d_in[4];
  const float* dn   = (const float*)d_in[5];
  float* out = (float*)d_out;

  char* ws = (char*)d_ws;
  int*      offs  = (int*)(ws + kOffsOff);
  int*      tok   = (int*)(ws + kTokOff);
  float*    tw    = (float*)(ws + kTwOff);
  _Float16* gated = (_Float16*)(ws + kGatedOff);

  hipMemsetAsync(d_out, 0, (size_t)kT * kH * sizeof(float), stream);
  route_kernel<<<1, 256, 0, stream>>>(ridx, rw, offs, tok, tw);
  gateup_kernel<<<dim3(32 * 16, kI / 64), 256, 0, stream>>>(hs, gup, offs, tok, gated);
  down_kernel<<<dim3(32 * 16, kH / 128), 256, 0, stream>>>(gated, dn, offs, tok, tw, out);
}